// Round 7
// baseline (9777.847 us; speedup 1.0000x reference)
//
#include <hip/hip_runtime.h>
#include <math.h>

// Round 16: unlock VGPRs for dec_all's pipelines. r15 diagnosis: phase A
// holds 40 live asm-written bf16x8 (160 VGPRs) but VGPR_Count=128 (the
// __launch_bounds__(512) default allocator target of 4 waves/SIMD) ->
// pipeline buffers SPILLED to scratch. Evidence: WRITE_SIZE 16.6MB/step vs
// 2.5MB algorithmic (=14MB/step scratch), and scratch buffer-ops corrupt our
// counted vmcnt -> serialization. LDS (151KB) already forces 1 block/CU =
// 2 waves/SIMD, where 256 VGPR/thread is free. Fix: __launch_bounds__(512,2)
// on dec_all. Everything else identical to r15 (enc_all r13-proven).

#define NB 128
#define NL 128
#define NH 1024
#define NA 256
#define NT 24
#define NM 151
#define ENCB 128
#define DECB 128

typedef __attribute__((ext_vector_type(8))) short bf16x8;
typedef __attribute__((ext_vector_type(8))) short s16x8;
typedef __attribute__((ext_vector_type(4))) float f32x4;

#define MFMA(a, b, acc) __builtin_amdgcn_mfma_f32_16x16x32_bf16(a, b, acc, 0, 0, 0)

#define I16_SCALE 32767.0f
#define I16_INV   (1.0f / 32767.0f)

__device__ __forceinline__ float sig_f(float x) {
  return 1.0f / (1.0f + __expf(-x));
}
__device__ __forceinline__ float tanh_f(float x) {
  x = fminf(9.0f, fmaxf(-9.0f, x));
  float e = __expf(2.0f * x);
  return (e - 1.0f) / (e + 1.0f);
}
__device__ __forceinline__ unsigned short f2bf(float f) {
  unsigned int u = __float_as_uint(f);
  u = (u + 0x7FFFu + ((u >> 16) & 1u)) >> 16;
  return (unsigned short)u;
}
__device__ __forceinline__ float bf2f(unsigned short u) {
  return __uint_as_float(((unsigned int)u) << 16);
}
__device__ __forceinline__ short f2i16(float f) {
  return (short)__float2int_rn(f * I16_SCALE);
}

// LLC-coherent 8B store of 4 packed ushorts (sc0sc1 write-through).
__device__ __forceinline__ void ast8(unsigned short* p, unsigned short a,
                                     unsigned short b, unsigned short cc,
                                     unsigned short d) {
  unsigned long long u = (unsigned long long)a | ((unsigned long long)b << 16) |
                         ((unsigned long long)cc << 32) |
                         ((unsigned long long)d << 48);
  __hip_atomic_store((unsigned long long*)p, u, __ATOMIC_RELAXED,
                     __HIP_MEMORY_SCOPE_AGENT);
}
__device__ __forceinline__ void astf(float* p, float v) {
  __hip_atomic_store((unsigned int*)p, __float_as_uint(v), __ATOMIC_RELAXED,
                     __HIP_MEMORY_SCOPE_AGENT);
}

// Pipelined loads. LLCLD*: sc0sc1 (LLC-coherent, bypass L1/L2).
// PLLD: plain cached (weights). Both counted in vmcnt by US, invisible to
// the compiler -> never mix with compiler-issued loads in a counted region.
#define LLCLD(dst, ptr) \
  asm volatile("global_load_dwordx4 %0, %1, off sc0 sc1" \
               : "=v"(dst) : "v"(ptr))
#define LLCLD4(dst, ptr) \
  asm volatile("global_load_dword %0, %1, off sc0 sc1" \
               : "=v"(dst) : "v"(ptr))
#define LLCLD8(dst, ptr) \
  asm volatile("global_load_dwordx2 %0, %1, off sc0 sc1" \
               : "=v"(dst) : "v"(ptr))
#define PLLD(dst, ptr) \
  asm volatile("global_load_dwordx4 %0, %1, off" \
               : "=v"(dst) : "v"(ptr))

#define WAITC(n)                                              \
  asm volatile("s_waitcnt vmcnt(" #n ")" ::: "memory");       \
  __builtin_amdgcn_sched_barrier(0)

// Flush-free grid barrier (one atomicAdd + poll per block).
__device__ __forceinline__ void gbar(unsigned int* bar, int t) {
  __syncthreads();
  if (threadIdx.x == 0) {
    unsigned int* cnt = bar + t * 32;
    __hip_atomic_fetch_add(cnt, 1u, __ATOMIC_RELAXED,
                           __HIP_MEMORY_SCOPE_AGENT);
    while (__hip_atomic_load(cnt, __ATOMIC_RELAXED,
                             __HIP_MEMORY_SCOPE_AGENT) < (unsigned)ENCB)
      __builtin_amdgcn_s_sleep(2);
  }
  __syncthreads();
}
__device__ __forceinline__ void gbar2(unsigned int* cell) {
  __syncthreads();
  if (threadIdx.x == 0) {
    __hip_atomic_fetch_add(cell, 1u, __ATOMIC_RELAXED,
                           __HIP_MEMORY_SCOPE_AGENT);
    while (__hip_atomic_load(cell, __ATOMIC_RELAXED,
                             __HIP_MEMORY_SCOPE_AGENT) < (unsigned)DECB)
      __builtin_amdgcn_s_sleep(2);
  }
  __syncthreads();
}

// ---------------------------------------------------------------------------
// conv front (proven round 1)
// ---------------------------------------------------------------------------
__global__ __launch_bounds__(128) void conv_front(
    const float* __restrict__ x,
    const float* __restrict__ w1, const float* __restrict__ b1,
    const float* __restrict__ w2, const float* __restrict__ b2,
    const float* __restrict__ w3, const float* __restrict__ b3,
    float* __restrict__ lstm_in)
{
  int b = blockIdx.x;
  int t = threadIdx.x;
  __shared__ float d[128][36];
  __shared__ float h1[128][34];
  __shared__ float h2[128][32];

  const float* xr = x + (size_t)(b * NL + t) * 48;
  #pragma unroll
  for (int f = 0; f < 36; ++f) d[t][f] = xr[f];
  __syncthreads();

  float acc[34];
  {
    float bias = b1[t];
    #pragma unroll
    for (int w = 0; w < 34; ++w) acc[w] = bias;
  }
  const float* wr = w1 + t * 384;
  for (int ci = 0; ci < 128; ++ci) {
    float row[36];
    #pragma unroll
    for (int f = 0; f < 36; ++f) row[f] = d[ci][f];
    float wa = wr[ci * 3 + 0], wb = wr[ci * 3 + 1], wc = wr[ci * 3 + 2];
    #pragma unroll
    for (int w = 0; w < 34; ++w)
      acc[w] += row[w] * wa + row[w + 1] * wb + row[w + 2] * wc;
  }
  #pragma unroll
  for (int w = 0; w < 34; ++w) {
    float z = acc[w];
    h1[t][w] = (z > 20.0f) ? z : log1pf(__expf(z));
  }
  __syncthreads();

  float acc2[32];
  {
    float bias = b2[t];
    #pragma unroll
    for (int w = 0; w < 32; ++w) acc2[w] = bias;
  }
  const float* wr2 = w2 + t * 384;
  for (int ci = 0; ci < 128; ++ci) {
    float row[34];
    #pragma unroll
    for (int f = 0; f < 34; ++f) row[f] = h1[ci][f];
    float wa = wr2[ci * 3 + 0], wb = wr2[ci * 3 + 1], wc = wr2[ci * 3 + 2];
    #pragma unroll
    for (int w = 0; w < 32; ++w)
      acc2[w] += row[w] * wa + row[w + 1] * wb + row[w + 2] * wc;
  }
  #pragma unroll
  for (int w = 0; w < 32; ++w) h2[t][w] = fmaxf(acc2[w], 0.0f);
  __syncthreads();

  float* outr = lstm_in + (size_t)(b * NL + t) * 18;
  #pragma unroll
  for (int e = 0; e < 6; ++e) {
    float s = b3[e];
    #pragma unroll
    for (int f = 0; f < 32; ++f) s += h2[t][f] * w3[e * 32 + f];
    outr[e] = s;
  }
  #pragma unroll
  for (int j = 0; j < 12; ++j) outr[6 + j] = xr[36 + j];
}

// ---------------------------------------------------------------------------
// Fragment-order transforms (4-column variant).
// ---------------------------------------------------------------------------
__global__ void frag_w4(const float* __restrict__ src, int K, int kshift,
                        unsigned short* __restrict__ hi,
                        unsigned short* __restrict__ lo, int ngroups)
{
  int o = blockIdx.x * 256 + threadIdx.x;
  if (o >= ngroups) return;
  int lane = o & 63;
  int ki = (o >> 6) & ((1 << kshift) - 1);
  int t2 = o >> (6 + kshift);
  int l15 = lane & 15, q = lane >> 4;
  int grow = (l15 >> 2) * 1024 + t2 * 4 + (l15 & 3);
  const float* s = src + (size_t)grow * K + ki * 32 + q * 8;
  unsigned short hv[8], lv[8];
  #pragma unroll
  for (int j = 0; j < 8; ++j) {
    float v = s[j];
    hv[j] = f2bf(v);
    lv[j] = f2bf(v - bf2f(hv[j]));
  }
  size_t e = (size_t)o * 8;
  *(ushort4*)(hi + e) = make_ushort4(hv[0], hv[1], hv[2], hv[3]);
  *(ushort4*)(hi + e + 4) = make_ushort4(hv[4], hv[5], hv[6], hv[7]);
  *(ushort4*)(lo + e) = make_ushort4(lv[0], lv[1], lv[2], lv[3]);
  *(ushort4*)(lo + e + 4) = make_ushort4(lv[4], lv[5], lv[6], lv[7]);
}

__global__ void frag_wqk(const float* __restrict__ wq,
                         const float* __restrict__ wk,
                         unsigned short* __restrict__ hi,
                         unsigned short* __restrict__ lo)
{
  int o = blockIdx.x * 256 + threadIdx.x;
  if (o >= 65536) return;
  int lane = o & 63;
  int ki = (o >> 6) & 31;
  int ntile = o >> 11;
  int l15 = lane & 15, q = lane >> 4;
  int row = ntile * 16 + l15;
  int k = ki * 32 + q * 8;
  const float* s = (row < 256) ? (wq + (size_t)row * 1024 + k)
                               : (wk + (size_t)(row - 256) * 1024 + k);
  unsigned short hv[8], lv[8];
  #pragma unroll
  for (int j = 0; j < 8; ++j) {
    float v = s[j];
    hv[j] = f2bf(v);
    lv[j] = f2bf(v - bf2f(hv[j]));
  }
  size_t e = (size_t)o * 8;
  *(ushort4*)(hi + e) = make_ushort4(hv[0], hv[1], hv[2], hv[3]);
  *(ushort4*)(hi + e + 4) = make_ushort4(hv[4], hv[5], hv[6], hv[7]);
  *(ushort4*)(lo + e) = make_ushort4(lv[0], lv[1], lv[2], lv[3]);
  *(ushort4*)(lo + e + 4) = make_ushort4(lv[4], lv[5], lv[6], lv[7]);
}

__global__ void frag_wx4(const float* __restrict__ wih,
                         unsigned short* __restrict__ hi,
                         unsigned short* __restrict__ lo)
{
  int o = blockIdx.x * 256 + threadIdx.x;
  if (o >= 16384) return;
  int lane = o & 63;
  int t2 = o >> 6;
  int l15 = lane & 15, q = lane >> 4;
  int grow = (l15 >> 2) * 1024 + t2 * 4 + (l15 & 3);
  unsigned short hv[8], lv[8];
  #pragma unroll
  for (int j = 0; j < 8; ++j) {
    int k = q * 8 + j;
    float v = (k < 18) ? wih[(size_t)grow * 18 + k] : 0.0f;
    hv[j] = f2bf(v);
    lv[j] = f2bf(v - bf2f(hv[j]));
  }
  size_t e = (size_t)o * 8;
  *(ushort4*)(hi + e) = make_ushort4(hv[0], hv[1], hv[2], hv[3]);
  *(ushort4*)(hi + e + 4) = make_ushort4(hv[4], hv[5], hv[6], hv[7]);
  *(ushort4*)(lo + e) = make_ushort4(lv[0], lv[1], lv[2], lv[3]);
  *(ushort4*)(lo + e + 4) = make_ushort4(lv[4], lv[5], lv[6], lv[7]);
}

__global__ void frag_xs(const float* __restrict__ lstm_in,
                        unsigned short* __restrict__ hi,
                        unsigned short* __restrict__ lo)
{
  int o = blockIdx.x * 256 + threadIdx.x;
  if (o >= 65536) return;
  int lane = o & 63;
  int btile = (o >> 6) & 7;
  int t = o >> 9;
  int l15 = lane & 15, q = lane >> 4;
  int b = btile * 16 + l15;
  unsigned short hv[8], lv[8];
  #pragma unroll
  for (int j = 0; j < 8; ++j) {
    int k = q * 8 + j;
    float v = (k < 18) ? lstm_in[(size_t)(b * NL + t) * 18 + k] : 0.0f;
    hv[j] = f2bf(v);
    lv[j] = f2bf(v - bf2f(hv[j]));
  }
  size_t e = (size_t)o * 8;
  *(ushort4*)(hi + e) = make_ushort4(hv[0], hv[1], hv[2], hv[3]);
  *(ushort4*)(hi + e + 4) = make_ushort4(hv[4], hv[5], hv[6], hv[7]);
  *(ushort4*)(lo + e) = make_ushort4(lv[0], lv[1], lv[2], lv[3]);
  *(ushort4*)(lo + e + 4) = make_ushort4(lv[4], lv[5], lv[6], lv[7]);
}

__global__ void init_all(float* __restrict__ c,
                         unsigned short* __restrict__ hhi0,
                         unsigned short* __restrict__ hlo0,
                         float* __restrict__ out,
                         unsigned int* __restrict__ bar) {
  int i = blockIdx.x * 256 + threadIdx.x;
  if (i < NB * NH) { c[i] = 0.0f; hhi0[i] = 0; hlo0[i] = 0; }
  if (i < NB * NT) out[i] = 0.0f;
  if (i < 8192) bar[i] = 0;
}

__global__ void zero_dbar(unsigned int* __restrict__ dbar) {
  dbar[threadIdx.x] = 0;
}

// ---------------------------------------------------------------------------
// enc_all (unchanged from round 13 -- 11.7us/step proven)
// ---------------------------------------------------------------------------
__global__ __launch_bounds__(512) void enc_all(
    unsigned short* __restrict__ hfA_hi, unsigned short* __restrict__ hfA_lo,
    unsigned short* __restrict__ hfB_hi, unsigned short* __restrict__ hfB_lo,
    const unsigned short* __restrict__ Wf_hi,
    const unsigned short* __restrict__ Wf_lo,
    const unsigned short* __restrict__ Wxf_hi,
    const unsigned short* __restrict__ Wxf_lo,
    const unsigned short* __restrict__ xsf_hi,
    const unsigned short* __restrict__ xsf_lo,
    const float* __restrict__ encb,
    float* __restrict__ c,
    short* __restrict__ buf,
    unsigned int* __restrict__ bar)
{
  __shared__ __align__(16) unsigned short SWh[32768];
  __shared__ __align__(16) unsigned short SWl[32768];
  __shared__ __align__(16) unsigned short SXh[1024];
  __shared__ __align__(16) unsigned short SXl[1024];
  __shared__ float G[128][33];

  int tid = threadIdx.x, bx = blockIdx.x;
  int w8 = tid >> 6, lane = tid & 63;
  int l15 = lane & 15, q4 = (lane >> 4) * 4;
  int ab = w8;
  int lane8 = lane * 8;
  size_t abl8 = (size_t)ab * 512 + lane8;

  {
    const unsigned short* gh = Wf_hi + (size_t)(bx * 2) * 16384;
    const unsigned short* gl = Wf_lo + (size_t)(bx * 2) * 16384;
    for (int i = tid * 8; i < 32768; i += 4096) {
      *(bf16x8*)(SWh + i) = *(const bf16x8*)(gh + i);
      *(bf16x8*)(SWl + i) = *(const bf16x8*)(gl + i);
    }
    if (tid < 128) {
      *(bf16x8*)(SXh + tid * 8) =
          *(const bf16x8*)(Wxf_hi + (size_t)(bx * 2) * 512 + tid * 8);
      *(bf16x8*)(SXl + tid * 8) =
          *(const bf16x8*)(Wxf_lo + (size_t)(bx * 2) * 512 + tid * 8);
    }
  }

  int eb = tid >> 1;
  int lt = tid & 1;
  int ekc = bx * 8 + lt * 4;
  float bias[4][4];
  #pragma unroll
  for (int q = 0; q < 4; ++q)
    #pragma unroll
    for (int j = 0; j < 4; ++j)
      bias[q][j] = encb[q * NH + ekc + j];
  float4 creg = make_float4(0.f, 0.f, 0.f, 0.f);
  int eki = ekc >> 5, eqq = (ekc >> 3) & 3, ej8 = ekc & 7;
  size_t efo = (size_t)eki * 4096 + (eb >> 4) * 512 +
               ((eb & 15) + 16 * eqq) * 8 + ej8;
  __syncthreads();

#define COMP1(kk) {                                                      \
    bf16x8 bh0 = *(const bf16x8*)(SWh + (kk) * 512 + lane8);             \
    bf16x8 bl0 = *(const bf16x8*)(SWl + (kk) * 512 + lane8);             \
    bf16x8 bh1 = *(const bf16x8*)(SWh + 16384 + (kk) * 512 + lane8);     \
    bf16x8 bl1 = *(const bf16x8*)(SWl + 16384 + (kk) * 512 + lane8);     \
    acc0 = MFMA(xh[kk], bh0, acc0); acc0 = MFMA(xl[kk], bh0, acc0);      \
    acc0 = MFMA(xh[kk], bl0, acc0);                                      \
    acc1 = MFMA(xh[kk], bh1, acc1); acc1 = MFMA(xl[kk], bh1, acc1);      \
    acc1 = MFMA(xh[kk], bl1, acc1); }

#define ISSUE(j) {                                                       \
    const unsigned short* p0 = hih + (size_t)(2 * (j)) * 4096 + abl8;    \
    const unsigned short* p1 = hil + (size_t)(2 * (j)) * 4096 + abl8;    \
    LLCLD(xh[2 * (j)], p0);                                              \
    LLCLD(xl[2 * (j)], p1);                                              \
    LLCLD(xh[2 * (j) + 1], p0 + 4096);                                   \
    LLCLD(xl[2 * (j) + 1], p1 + 4096); }

  for (int t = 0; t < NL; ++t) {
    const unsigned short* hih = (t & 1) ? hfB_hi : hfA_hi;
    const unsigned short* hil = (t & 1) ? hfB_lo : hfA_lo;
    unsigned short* hoh = (t & 1) ? hfA_hi : hfB_hi;
    unsigned short* hol = (t & 1) ? hfA_lo : hfB_lo;

    f32x4 acc0 = {0,0,0,0}, acc1 = {0,0,0,0};

    {
      size_t xo = ((size_t)t * 8 + ab) * 512 + lane8;
      bf16x8 sh = *(const bf16x8*)(xsf_hi + xo);
      bf16x8 sl = *(const bf16x8*)(xsf_lo + xo);
      bf16x8 y0h = *(const bf16x8*)(SXh + lane8);
      bf16x8 y0l = *(const bf16x8*)(SXl + lane8);
      bf16x8 y1h = *(const bf16x8*)(SXh + 512 + lane8);
      bf16x8 y1l = *(const bf16x8*)(SXl + 512 + lane8);
      acc0 = MFMA(sh, y0h, acc0); acc0 = MFMA(sl, y0h, acc0);
      acc0 = MFMA(sh, y0l, acc0);
      acc1 = MFMA(sh, y1h, acc1); acc1 = MFMA(sl, y1h, acc1);
      acc1 = MFMA(sh, y1l, acc1);
    }
    WAITC(0);

    bf16x8 xh[32], xl[32];
    ISSUE(0); ISSUE(1); ISSUE(2); ISSUE(3);
    WAITC(12); ISSUE(4);  COMP1(0);  COMP1(1);
    WAITC(12); ISSUE(5);  COMP1(2);  COMP1(3);
    WAITC(12); ISSUE(6);  COMP1(4);  COMP1(5);
    WAITC(12); ISSUE(7);  COMP1(6);  COMP1(7);
    WAITC(12); ISSUE(8);  COMP1(8);  COMP1(9);
    WAITC(12); ISSUE(9);  COMP1(10); COMP1(11);
    WAITC(12); ISSUE(10); COMP1(12); COMP1(13);
    WAITC(12); ISSUE(11); COMP1(14); COMP1(15);
    WAITC(12); ISSUE(12); COMP1(16); COMP1(17);
    WAITC(12); ISSUE(13); COMP1(18); COMP1(19);
    WAITC(12); ISSUE(14); COMP1(20); COMP1(21);
    WAITC(12); ISSUE(15); COMP1(22); COMP1(23);
    WAITC(12); COMP1(24); COMP1(25);
    WAITC(8);  COMP1(26); COMP1(27);
    WAITC(4);  COMP1(28); COMP1(29);
    WAITC(0);  COMP1(30); COMP1(31);

    #pragma unroll
    for (int r = 0; r < 4; ++r) {
      G[ab * 16 + q4 + r][l15]      = acc0[r];
      G[ab * 16 + q4 + r][16 + l15] = acc1[r];
    }
    __syncthreads();

    if (tid < 256) {
      float rh[4];
      float* cp = &creg.x;
      #pragma unroll
      for (int j = 0; j < 4; ++j) {
        float gate[4];
        #pragma unroll
        for (int q = 0; q < 4; ++q)
          gate[q] = G[eb][lt * 16 + q * 4 + j] + bias[q][j];
        float cn = sig_f(gate[1]) * cp[j] + sig_f(gate[0]) * tanh_f(gate[2]);
        float hn = sig_f(gate[3]) * tanh_f(cn);
        cp[j] = cn; rh[j] = hn;
      }
      unsigned short hh[4], hl[4];
      short hq[4];
      #pragma unroll
      for (int j = 0; j < 4; ++j) {
        hh[j] = f2bf(rh[j]);
        hl[j] = f2bf(rh[j] - bf2f(hh[j]));
        hq[j] = f2i16(rh[j]);
      }
      ast8(hoh + efo, hh[0], hh[1], hh[2], hh[3]);
      ast8(hol + efo, hl[0], hl[1], hl[2], hl[3]);
      *(short4*)(buf + (size_t)(eb * NM + t) * NH + ekc) =
          make_short4(hq[0], hq[1], hq[2], hq[3]);
    }
    if (t < NL - 1) gbar(bar, t);
  }
  if (tid < 256)
    *(float4*)(c + (size_t)eb * NH + ekc) = creg;
#undef COMP1
#undef ISSUE
}

// ---------------------------------------------------------------------------
// dec_prep: read final h (frag) + c (row-major) -> q frag rows 2b / 2b+1.
// ---------------------------------------------------------------------------
__global__ __launch_bounds__(256) void dec_prep(
    const unsigned short* __restrict__ hf_hi,
    const unsigned short* __restrict__ hf_lo,
    const float* __restrict__ c,
    unsigned short* __restrict__ qhi, unsigned short* __restrict__ qlo)
{
  int b = blockIdx.x;
  int j4 = threadIdx.x * 4;
  int ki = j4 >> 5, qq = (j4 >> 3) & 3, j8 = j4 & 7;
  size_t fh = (size_t)ki * 4096 + (b >> 4) * 512 + ((b & 15) + 16 * qq) * 8 + j8;
  ushort4 hv = *(const ushort4*)(hf_hi + fh);
  ushort4 lv = *(const ushort4*)(hf_lo + fh);
  float4 cv = *(const float4*)(c + (size_t)b * NH + j4);
  unsigned short ch[4], cl[4];
  float cf[4] = {cv.x, cv.y, cv.z, cv.w};
  #pragma unroll
  for (int k = 0; k < 4; ++k) {
    ch[k] = f2bf(cf[k]); cl[k] = f2bf(cf[k] - bf2f(ch[k]));
  }
  int rt = (2 * b) >> 4;
  int rl = ((2 * b) & 15) + 16 * qq;
  size_t fq = (size_t)ki * 8192 + rt * 512 + rl * 8 + j8;
  *(ushort4*)(qhi + fq) = hv;
  *(ushort4*)(qlo + fq) = lv;
  *(ushort4*)(qhi + fq + 8) = make_ushort4(ch[0], ch[1], ch[2], ch[3]);
  *(ushort4*)(qlo + fq + 8) = make_ushort4(cl[0], cl[1], cl[2], cl[3]);
}

// ---------------------------------------------------------------------------
// Bulk kp: kp = buf(i16, row-major) @ Wk^T (frag B, 2-term). grid(302,4).
// ---------------------------------------------------------------------------
__global__ __launch_bounds__(256) void gemm_kp(
    const short* __restrict__ A,
    const unsigned short* __restrict__ Bhi,
    const unsigned short* __restrict__ Blo,
    unsigned short* __restrict__ C)
{
  int tid = threadIdx.x;
  int w = tid >> 6, lane = tid & 63;
  int l15 = lane & 15, q8 = (lane >> 4) * 8, q4 = (lane >> 4) * 4;
  size_t m0 = (size_t)blockIdx.x * 64;
  int n0 = blockIdx.y * 64 + w * 16;
  int ntile = 16 + blockIdx.y * 4 + w;

  const unsigned short* Bh = Bhi + (size_t)ntile * 16384 + lane * 8;
  const unsigned short* Bl = Blo + (size_t)ntile * 16384 + lane * 8;
  f32x4 acc[4] = {{0,0,0,0},{0,0,0,0},{0,0,0,0},{0,0,0,0}};
  for (int ki = 0; ki < 32; ++ki) {
    int ko = ki * 32 + q8;
    size_t bo = (size_t)ki * 512;
    bf16x8 bh = *(const bf16x8*)(Bh + bo);
    bf16x8 bl = *(const bf16x8*)(Bl + bo);
    #pragma unroll
    for (int i = 0; i < 4; ++i) {
      s16x8 av = *(const s16x8*)(A + (m0 + 16 * i + l15) * (size_t)NH + ko);
      bf16x8 ah;
      #pragma unroll
      for (int k = 0; k < 8; ++k)
        ah[k] = (short)f2bf((float)av[k] * I16_INV);
      acc[i] = MFMA(ah, bh, acc[i]);
      acc[i] = MFMA(ah, bl, acc[i]);
    }
  }
  #pragma unroll
  for (int i = 0; i < 4; ++i)
    #pragma unroll
    for (int r = 0; r < 4; ++r)
      C[(m0 + 16 * i + q4 + r) * NA + n0 + l15] = f2bf(acc[i][r]);
}

// ---------------------------------------------------------------------------
// dec_all v3: identical to r15 except __launch_bounds__(512, 2) -- 1 block/CU
// (LDS-forced) = 2 waves/SIMD -> 256 VGPR budget, no pipeline spills.
// ---------------------------------------------------------------------------
__global__ __launch_bounds__(512, 2) void dec_all(
    unsigned short* __restrict__ Xfh, unsigned short* __restrict__ Xfl,
    unsigned short* __restrict__ qAh, unsigned short* __restrict__ qAl,
    unsigned short* __restrict__ qBh, unsigned short* __restrict__ qBl,
    const unsigned short* __restrict__ Wqh, const unsigned short* __restrict__ Wql,
    const unsigned short* __restrict__ WdxHg, const unsigned short* __restrict__ WdxLg,
    const unsigned short* __restrict__ WdhHg, const unsigned short* __restrict__ WdhLg,
    const float* __restrict__ decb, const float* __restrict__ cin,
    short* __restrict__ buf, unsigned short* __restrict__ kp,
    float* __restrict__ qkout, const float* __restrict__ Wv,
    const float* __restrict__ out_w, const float* __restrict__ out_b,
    float* __restrict__ out, unsigned int* __restrict__ dbar)
{
  __shared__ __align__(16) unsigned short SDh[32768];
  __shared__ __align__(16) unsigned short SDl[32768];
  __shared__ float G[128][33];
  __shared__ float sWv[256], q0s[256], q1s[256], kNs[256];
  __shared__ float sc2[2][NM + 1];
  __shared__ float w0s[NM + 1], w1s[NM + 1];

  int tid = threadIdx.x, bx = blockIdx.x;
  int w8 = tid >> 6, lane = tid & 63;
  int l15 = lane & 15, q4 = (lane >> 4) * 4;
  int ab = w8;
  int lane8 = lane * 8;
  int b = bx;

  // stage Wdh slice (128 KB) into LDS once
  {
    const unsigned short* gh = WdhHg + (size_t)bx * 32768;
    const unsigned short* gl = WdhLg + (size_t)bx * 32768;
    for (int i = tid * 8; i < 32768; i += 4096) {
      *(bf16x8*)(SDh + i) = *(const bf16x8*)(gh + i);
      *(bf16x8*)(SDl + i) = *(const bf16x8*)(gl + i);
    }
  }
  if (tid < 256) sWv[tid] = Wv[tid];

  int eb = tid >> 1, lt = tid & 1;
  int ekc = bx * 8 + lt * 4;
  float dbias[4][4], ow4[4];
  float4 creg = make_float4(0.f, 0.f, 0.f, 0.f);
  if (tid < 256) {
    #pragma unroll
    for (int q = 0; q < 4; ++q)
      #pragma unroll
      for (int j = 0; j < 4; ++j)
        dbias[q][j] = decb[q * NH + ekc + j];
    #pragma unroll
    for (int j = 0; j < 4; ++j) ow4[j] = out_w[ekc + j];
    creg = *(const float4*)(cin + (size_t)eb * NH + ekc);
  }
  float ob = out_b[0];
  int eki = ekc >> 5, eqq = (ekc >> 3) & 3, ej8 = ekc & 7;
  int ert = (2 * eb) >> 4;
  int erl = ((2 * eb) & 15) + 16 * eqq;
  size_t efq = (size_t)eki * 8192 + ert * 512 + erl * 8 + ej8;
  __syncthreads();

  for (int t = 0; t < NT; ++t) {
    const unsigned short* qih = (t & 1) ? qBh : qAh;
    const unsigned short* qil = (t & 1) ? qBl : qAl;
    unsigned short* qoh = (t & 1) ? qAh : qBh;
    unsigned short* qol = (t & 1) ? qAl : qBl;
    int Mt = NL + t;

    // ============ phase A: qkout = q @ Wqk^T (all-asm, 5-win x 2ki) ========
    if (w8 < 4) {
      int g = bx * 4 + w8;
      int mtile = g >> 5, ntile = g & 31;
      const unsigned short* Ah = qih + (size_t)mtile * 512 + lane8;
      const unsigned short* Al = qil + (size_t)mtile * 512 + lane8;
      const unsigned short* Bh = Wqh + (size_t)ntile * 16384 + lane8;
      const unsigned short* Bl = Wql + (size_t)ntile * 16384 + lane8;
      f32x4 acc = {0, 0, 0, 0};
      bf16x8 axh[10], axl[10], awh[10], awl[10];
#define AISS(J) { _Pragma("unroll") for (int i_ = 0; i_ < 2; ++i_) {     \
      size_t ko = (size_t)((J) * 2 + i_); int w_ = ((J) % 5) * 2 + i_;   \
      LLCLD(axh[w_], Ah + ko * 8192); LLCLD(axl[w_], Al + ko * 8192);    \
      PLLD(awh[w_], Bh + ko * 512);   PLLD(awl[w_], Bl + ko * 512); } }
      AISS(0); AISS(1); AISS(2); AISS(3); AISS(4);
      #pragma unroll
      for (int jj = 0; jj < 16; ++jj) {
        if (jj <= 11)      { WAITC(32); }
        else if (jj == 12) { WAITC(24); }
        else if (jj == 13) { WAITC(16); }
        else if (jj == 14) { WAITC(8); }
        else               { WAITC(0); }
        #pragma unroll
        for (int i_ = 0; i_ < 2; ++i_) {
          int w_ = (jj % 5) * 2 + i_;
          acc = MFMA(axh[w_], awh[w_], acc);
          acc = MFMA(axl[w_], awh[w_], acc);
          acc = MFMA(axh[w_], awl[w_], acc);
        }
        if (jj <= 10) { AISS(jj + 5); }
      }
#undef AISS
      #pragma unroll
      for (int r = 0; r < 4; ++r)
        astf(qkout + (size_t)(mtile * 16 + q4 + r) * 512 + ntile * 16 + l15,
             acc[r]);
    }
    gbar2(dbar + t * 3 + 0);

    // ================= phase B: attention =================
    if (tid < 256) {
      unsigned int u0, u1, u2;
      LLCLD4(u0, (const float*)qkout + (size_t)(2 * b) * 512 + tid);
      LLCLD4(u1, (const float*)qkout + (size_t)(2 * b + 1) * 512 + tid);
      LLCLD4(u2, (const float*)qkout + (size_t)(2 * b) * 512 + 256 + tid);
      WAITC(0);
      q0s[tid] = __uint_as_float(u0);
      q1s[tid] = __uint_as_float(u1);
      float kn = __uint_as_float(u2);
      kNs[tid] = kn;
      if (t < NT - 1)   // row 150 hosts dbar; dead write skipped
        kp[((size_t)(b * NM) + (NL - 1 + t)) * NA + tid] = f2bf(kn);
    }
    __syncthreads();

    for (int idx = tid; idx < 2 * Mt; idx += 512) {
      int m = idx >> 1, n = idx & 1;
      const float* q = n ? q1s : q0s;
      float s = 0.0f;
      if (m == Mt - 1) {
        for (int a = 0; a < NA; ++a) s += tanh_f(q[a] + kNs[a]) * sWv[a];
      } else {
        const unsigned short* kpr = kp + ((size_t)(b * NM) + m) * NA;
        for (int a = 0; a < NA; a += 4) {
          ushort4 kv = *(const ushort4*)(kpr + a);
          s += tanh_f(q[a + 0] + bf2f(kv.x)) * sWv[a + 0];
          s += tanh_f(q[a + 1] + bf2f(kv.y)) * sWv[a + 1];
          s += tanh_f(q[a + 2] + bf2f(kv.z)) * sWv[a + 2];
          s += tanh_f(q[a + 3] + bf2f(kv.w)) * sWv[a + 3];
        }
      }
      sc2[n][m] = s;
    }
    __syncthreads();
    for (int m = tid; m < Mt; m += 512) {
      float s0 = sc2[0][m], s1 = sc2[1][m];
      float mx = fmaxf(s0, s1);
      float e0 = __expf(s0 - mx), e1 = __expf(s1 - mx);
      float inv = 1.0f / (e0 + e1);
      w0s[m] = e0 * inv;
      w1s[m] = e1 * inv;
    }
    for (int m = Mt + tid; m < NM; m += 512) { w0s[m] = 0.f; w1s[m] = 0.f; }
    __syncthreads();

    // PV: all 512 threads (tid<256 -> head 0, tid>=256 -> head 1)
    {
      int n = tid >> 8;
      int cc = (tid & 255) * 4;
      const float* ws = n ? w1s : w0s;
      float4 a = {0, 0, 0, 0};
      const short* bb = buf + ((size_t)b * NM) * NH + cc;
      for (int m = 0; m < NL; ++m) {
        short4 v = *(const short4*)(bb + (size_t)m * NH);
        float w = ws[m];
        a.x += (float)v.x * I16_INV * w; a.y += (float)v.y * I16_INV * w;
        a.z += (float)v.z * I16_INV * w; a.w += (float)v.w * I16_INV * w;
      }
      {
        union U8 { unsigned long long u; short4 s; } tv[23];
        #pragma unroll
        for (int m = 0; m < 23; ++m)
          LLCLD8(tv[m].u, bb + (size_t)(NL + m) * NH);
        WAITC(0);
        #pragma unroll
        for (int m = 0; m < 23; ++m) {
          short4 v = tv[m].s;
          float w = ws[NL + m];
          a.x += (float)v.x * I16_INV * w; a.y += (float)v.y * I16_INV * w;
          a.z += (float)v.z * I16_INV * w; a.w += (float)v.w * I16_INV * w;
        }
      }
      float av[4] = {a.x, a.y, a.z, a.w};
      unsigned short h4[4], l4[4];
      #pragma unroll
      for (int k = 0; k < 4; ++k) {
        h4[k] = f2bf(av[k]); l4[k] = f2bf(av[k] - bf2f(h4[k]));
      }
      int ke = n * 1024 + cc;
      size_t fo = (size_t)(ke >> 5) * 4096 + (b >> 4) * 512 +
                  ((b & 15) + 16 * ((ke >> 3) & 3)) * 8 + (ke & 7);
      ast8(Xfh + fo, h4[0], h4[1], h4[2], h4[3]);
      ast8(Xfl + fo, l4[0], l4[1], l4[2], l4[3]);
    }
    gbar2(dbar + t * 3 + 1);

    // ================= phase C: LSTM =================
    {
      f32x4 acc0 = {0,0,0,0}, acc1 = {0,0,0,0};
      // ctx part (64 ki): all-asm 3-win x 2ki pipeline
      {
        const unsigned short* XAh = Xfh + (size_t)ab * 512 + lane8;
        const unsigned short* XAl = Xfl + (size_t)ab * 512 + lane8;
        const unsigned short* WXH = WdxHg + (size_t)bx * 65536 + lane8;
        const unsigned short* WXL = WdxLg + (size_t)bx * 65536 + lane8;
        bf16x8 cxh[6], cxl[6], c0h[6], c0l[6], c1h[6], c1l[6];
#define CISS(J) { _Pragma("unroll") for (int i_ = 0; i_ < 2; ++i_) {       \
        size_t ko = (size_t)((J) * 2 + i_); int w_ = ((J) % 3) * 2 + i_;   \
        LLCLD(cxh[w_], XAh + ko * 4096); LLCLD(cxl[w_], XAl + ko * 4096);  \
        PLLD(c0h[w_], WXH + ko * 512);   PLLD(c0l[w_], WXL + ko * 512);    \
        PLLD(c1h[w_], WXH + 32768 + ko * 512);                             \
        PLLD(c1l[w_], WXL + 32768 + ko * 512); } }
        CISS(0); CISS(1); CISS(2);
        #pragma unroll
        for (int jj = 0; jj < 32; ++jj) {
          if (jj <= 29)      { WAITC(24); }
          else if (jj == 30) { WAITC(12); }
          else               { WAITC(0); }
          #pragma unroll
          for (int i_ = 0; i_ < 2; ++i_) {
            int w_ = (jj % 3) * 2 + i_;
            acc0 = MFMA(cxh[w_], c0h[w_], acc0);
            acc0 = MFMA(cxl[w_], c0h[w_], acc0);
            acc0 = MFMA(cxh[w_], c0l[w_], acc0);
            acc1 = MFMA(cxh[w_], c1h[w_], acc1);
            acc1 = MFMA(cxl[w_], c1h[w_], acc1);
            acc1 = MFMA(cxh[w_], c1l[w_], acc1);
          }
          if (jj <= 28) { CISS(jj + 3); }
        }
#undef CISS
      }
      // h-part (32 ki): A LLC 8-ki chunks (2-win), W from LDS
      {
        const unsigned short* QAh = qih +
            (size_t)(2 * ab + (l15 >> 3)) * 512 +
            (2 * (l15 & 7) + 16 * (lane >> 4)) * 8;
        const unsigned short* QAl = qil +
            (size_t)(2 * ab + (l15 >> 3)) * 512 +
            (2 * (l15 & 7) + 16 * (lane >> 4)) * 8;
        bf16x8 axh[16], axl[16];
#define HISS(P, J) { _Pragma("unroll") for (int i_ = 0; i_ < 8; ++i_) {    \
        LLCLD(axh[(P) * 8 + i_], QAh + (size_t)((J) * 8 + i_) * 8192);     \
        LLCLD(axl[(P) * 8 + i_], QAl + (size_t)((J) * 8 + i_) * 8192); } }
        HISS(0, 0);
        #pragma unroll
        for (int j = 0; j < 4; ++j) {
          if (j < 3) { HISS((j + 1) & 1, j + 1); }
          if (j < 3) { WAITC(16); } else { WAITC(0); }
          #pragma unroll
          for (int i_ = 0; i_ < 8; ++i_) {
            int bo = (j * 8 + i_) * 512 + lane8;
            bf16x8 bh0 = *(const bf16x8*)(SDh + bo);
            bf16x8 bl0 = *(const bf16x8*)(SDl + bo);
            bf16x8 bh1 = *(const bf16x8*)(SDh + 16384 + bo);
            bf16x8 bl1 = *(const bf16x8*)(SDl + 16384 + bo);
            bf16x8 xh_ = axh[(j & 1) * 8 + i_];
            bf16x8 xl_ = axl[(j & 1) * 8 + i_];
            acc0 = MFMA(xh_, bh0, acc0); acc0 = MFMA(xl_, bh0, acc0);
            acc0 = MFMA(xh_, bl0, acc0);
            acc1 = MFMA(xh_, bh1, acc1); acc1 = MFMA(xl_, bh1, acc1);
            acc1 = MFMA(xh_, bl1, acc1);
          }
        }
#undef HISS
      }
      #pragma unroll
      for (int r = 0; r < 4; ++r) {
        G[ab * 16 + q4 + r][l15]      = acc0[r];
        G[ab * 16 + q4 + r][16 + l15] = acc1[r];
      }
    }
    __syncthreads();

    if (tid < 256) {
      float rh[4], rc[4];
      float* cp = &creg.x;
      #pragma unroll
      for (int j = 0; j < 4; ++j) {
        float gate[4];
        #pragma unroll
        for (int q = 0; q < 4; ++q)
          gate[q] = G[eb][lt * 16 + q * 4 + j] + dbias[q][j];
        float cn = sig_f(gate[1]) * cp[j] + sig_f(gate[0]) * tanh_f(gate[2]);
        float hn = sig_f(gate[3]) * tanh_f(cn);
        cp[j] = cn; rc[j] = cn; rh[j] = hn;
      }
      float py = 0.0f;
      #pragma unroll
      for (int j = 0; j < 4; ++j) py += rh[j] * ow4[j];
      if (bx == 0 && lt == 0) py += ob;
      atomicAdd(&out[eb * NT + t], py);

      if (t < NT - 1) {
        unsigned short hh[4], hl[4], ch[4], cl[4];
        short hq[4];
        #pragma unroll
        for (int j = 0; j < 4; ++j) {
          hh[j] = f2bf(rh[j]); hl[j] = f2bf(rh[j] - bf2f(hh[j]));
          ch[j] = f2bf(rc[j]); cl[j] = f2bf(rc[j] - bf2f(ch[j]));
          hq[j] = f2i16(rh[j]);
        }
        ast8((unsigned short*)(buf + (size_t)(eb * NM + NL + t) * NH + ekc),
             (unsigned short)hq[0], (unsigned short)hq[1],
             (unsigned short)hq[2], (unsigned short)hq[3]);
        ast8(qoh + efq, hh[0], hh[1], hh[2], hh[3]);
        ast8(qol + efq, hl[0], hl[1], hl[2], hl[3]);
        ast8(qoh + efq + 8, ch[0], ch[1], ch[2], ch[3]);
        ast8(qol + efq + 8, cl[0], cl[1], cl[2], cl[3]);
      }
    }
    if (t < NT - 1) gbar2(dbar + t * 3 + 2);
  }
}

// ---------------------------------------------------------------------------
extern "C" void kernel_launch(void* const* d_in, const int* in_sizes, int n_in,
                              void* d_out, int out_size, void* d_ws, size_t ws_size,
                              hipStream_t stream) {
  const float* x       = (const float*)d_in[0];
  const float* conv1_w = (const float*)d_in[1];
  const float* conv1_b = (const float*)d_in[2];
  const float* conv2_w = (const float*)d_in[3];
  const float* conv2_b = (const float*)d_in[4];
  const float* lin3_w  = (const float*)d_in[5];
  const float* lin3_b  = (const float*)d_in[6];
  const float* enc_Wih = (const float*)d_in[7];
  const float* enc_Whh = (const float*)d_in[8];
  const float* enc_b   = (const float*)d_in[9];
  const float* attn_Wq = (const float*)d_in[10];
  const float* attn_Wk = (const float*)d_in[11];
  const float* attn_Wv = (const float*)d_in[12];
  const float* dec_Wih = (const float*)d_in[13];
  const float* dec_Whh = (const float*)d_in[14];
  const float* dec_b   = (const float*)d_in[15];
  const float* out_w   = (const float*)d_in[16];
  const float* out_b   = (const float*)d_in[17];
  float* out = (float*)d_out;

  // ---- workspace carve: identical totals to rounds 6-15 ----
  unsigned short* W = (unsigned short*)d_ws;
  short*          buf    = (short*)W;                  // 19,791,872 i16
  unsigned short* kp     = W + (size_t)19791872;       // 4,947,968
  unsigned short* qA_hi  = kp + 4947968;               // 262,144 (q frag)
  unsigned short* qA_lo  = qA_hi + 262144;
  unsigned short* qB_hi  = qA_lo + 262144;
  unsigned short* qB_lo  = qB_hi + 262144;
  unsigned short* Xf_hi  = qB_lo + 262144;             // 262,144 (ctx frag)
  unsigned short* Xf_lo  = Xf_hi + 262144;
  unsigned short* Wqkf_hi = Xf_lo + 262144;            // 524,288 (frag)
  unsigned short* Wqkf_lo = Wqkf_hi + 524288;
  unsigned short* Wdhf_hi = Wqkf_lo + 524288;          // 4,194,304 (enc Whh first)
  unsigned short* Wdhf_lo = Wdhf_hi + 4194304;
  unsigned short* Wdxf_hi = Wdhf_lo + 4194304;         // 8,388,608
  unsigned short* Wdxf_lo = Wdxf_hi + 8388608;         // 8,388,608
  float* c     = (float*)(Wdxf_lo + 8388608);          // 131,072 f
  float* qkout = c + 131072;                           // 131,072 f
  // encoder-phase overlays in Wdxf regions (dead until dec weight transform):
  unsigned short* hfA_hi = Wdxf_hi;                    // 131,072 (h frag)
  unsigned short* hfA_lo = Wdxf_hi + 131072;
  unsigned short* hfB_hi = Wdxf_hi + 262144;
  unsigned short* hfB_lo = Wdxf_hi + 393216;
  unsigned short* xsf_hi = Wdxf_hi + 524288;           // 524,288
  unsigned short* xsf_lo = xsf_hi + 524288;            // 524,288
  unsigned short* Wxf_hi = xsf_lo + 524288;            // 131,072
  unsigned short* Wxf_lo = Wxf_hi + 131072;            // 131,072
  float* lstm_in = (float*)Wdxf_lo;                    // 294,912 f
  // enc barrier: dead space inside Wdxf_lo overlay (valid pre-transform)
  unsigned int* bar = (unsigned int*)(Wdxf_lo + 1048576);
  // dec barrier: kp row 150 of batch 0 (never read; re-zeroed post-gemm_kp)
  unsigned int* dbar = (unsigned int*)(kp + (size_t)150 * NA);

  init_all<<<512, 256, 0, stream>>>(c, hfA_hi, hfA_lo, out, bar);
  conv_front<<<NB, 128, 0, stream>>>(x, conv1_w, conv1_b, conv2_w, conv2_b,
                                     lin3_w, lin3_b, lstm_in);
  frag_xs<<<256, 256, 0, stream>>>(lstm_in, xsf_hi, xsf_lo);
  frag_wx4<<<64, 256, 0, stream>>>(enc_Wih, Wxf_hi, Wxf_lo);
  frag_w4<<<2048, 256, 0, stream>>>(enc_Whh, 1024, 5, Wdhf_hi, Wdhf_lo, 524288);
  frag_wqk<<<256, 256, 0, stream>>>(attn_Wq, attn_Wk, Wqkf_hi, Wqkf_lo);

  // Encoder: 128 steps, ONE persistent cooperative launch
  {
    void* ea[] = {
      (void*)&hfA_hi, (void*)&hfA_lo, (void*)&hfB_hi, (void*)&hfB_lo,
      (void*)&Wdhf_hi, (void*)&Wdhf_lo, (void*)&Wxf_hi, (void*)&Wxf_lo,
      (void*)&xsf_hi, (void*)&xsf_lo, (void*)&enc_b, (void*)&c, (void*)&buf,
      (void*)&bar
    };
    hipLaunchCooperativeKernel((void*)enc_all, dim3(ENCB), dim3(512), ea, 0,
                               stream);
  }
  // t=127 (odd) wrote hfA -> final h there

  dec_prep<<<NB, 256, 0, stream>>>(hfA_hi, hfA_lo, c, qA_hi, qA_lo);
  gemm_kp<<<dim3(302, 4), 256, 0, stream>>>(buf, Wqkf_hi, Wqkf_lo, kp);
  zero_dbar<<<1, 128, 0, stream>>>(dbar);

  // decoder weight transforms (overwrite encoder overlays)
  frag_w4<<<4096, 256, 0, stream>>>(dec_Wih, 2048, 6, Wdxf_hi, Wdxf_lo, 1048576);
  frag_w4<<<2048, 256, 0, stream>>>(dec_Whh, 1024, 5, Wdhf_hi, Wdhf_lo, 524288);

  // Decoder: 24 steps, ONE persistent cooperative launch
  {
    void* da[] = {
      (void*)&Xf_hi, (void*)&Xf_lo, (void*)&qA_hi, (void*)&qA_lo,
      (void*)&qB_hi, (void*)&qB_lo, (void*)&Wqkf_hi, (void*)&Wqkf_lo,
      (void*)&Wdxf_hi, (void*)&Wdxf_lo, (void*)&Wdhf_hi, (void*)&Wdhf_lo,
      (void*)&dec_b, (void*)&c, (void*)&buf, (void*)&kp, (void*)&qkout,
      (void*)&attn_Wv, (void*)&out_w, (void*)&out_b, (void*)&out,
      (void*)&dbar
    };
    hipLaunchCooperativeKernel((void*)dec_all, dim3(DECB), dim3(512), da, 0,
                               stream);
  }
}

// Round 8
// 8285.760 us; speedup vs baseline: 1.1801x; 1.1801x over previous
//
#include <hip/hip_runtime.h>
#include <math.h>

// Round 17: dec_all redesigned to FIT 128 VGPRs (stop fighting the allocator;
// r15/r16: 40 live bf16x8 = 160 VGPR > 128 cap -> spills -> WRITE_SIZE
// +13.7MB/step, vmcnt corrupted). New geometry mirrors proven enc_all
// (88 VGPR, 11.7us/step): 256 blocks x 4 cols, wave = 1 batch-tile x 1 tile
// (single acc). Phase A: K-split over 8 waves (2-deep x 2ki = 16 live) + LDS
// reduce. Phase C ctx: 3-deep x 2ki = 24 live; h: 2-deep x 4ki = 16 live.
// Epilogue cold state reloaded per step. gbar2 DECB=256. enc_all unchanged.

#define NB 128
#define NL 128
#define NH 1024
#define NA 256
#define NT 24
#define NM 151
#define ENCB 128
#define DECB 256

typedef __attribute__((ext_vector_type(8))) short bf16x8;
typedef __attribute__((ext_vector_type(8))) short s16x8;
typedef __attribute__((ext_vector_type(4))) float f32x4;

#define MFMA(a, b, acc) __builtin_amdgcn_mfma_f32_16x16x32_bf16(a, b, acc, 0, 0, 0)

#define I16_SCALE 32767.0f
#define I16_INV   (1.0f / 32767.0f)

__device__ __forceinline__ float sig_f(float x) {
  return 1.0f / (1.0f + __expf(-x));
}
__device__ __forceinline__ float tanh_f(float x) {
  x = fminf(9.0f, fmaxf(-9.0f, x));
  float e = __expf(2.0f * x);
  return (e - 1.0f) / (e + 1.0f);
}
__device__ __forceinline__ unsigned short f2bf(float f) {
  unsigned int u = __float_as_uint(f);
  u = (u + 0x7FFFu + ((u >> 16) & 1u)) >> 16;
  return (unsigned short)u;
}
__device__ __forceinline__ float bf2f(unsigned short u) {
  return __uint_as_float(((unsigned int)u) << 16);
}
__device__ __forceinline__ short f2i16(float f) {
  return (short)__float2int_rn(f * I16_SCALE);
}

// LLC-coherent 8B store of 4 packed ushorts (sc0sc1 write-through).
__device__ __forceinline__ void ast8(unsigned short* p, unsigned short a,
                                     unsigned short b, unsigned short cc,
                                     unsigned short d) {
  unsigned long long u = (unsigned long long)a | ((unsigned long long)b << 16) |
                         ((unsigned long long)cc << 32) |
                         ((unsigned long long)d << 48);
  __hip_atomic_store((unsigned long long*)p, u, __ATOMIC_RELAXED,
                     __HIP_MEMORY_SCOPE_AGENT);
}
__device__ __forceinline__ void astf(float* p, float v) {
  __hip_atomic_store((unsigned int*)p, __float_as_uint(v), __ATOMIC_RELAXED,
                     __HIP_MEMORY_SCOPE_AGENT);
}

// Pipelined loads. LLCLD*: sc0sc1 (LLC-coherent, bypass L1/L2).
// PLLD: plain cached (weights). Both asm-issued -> our vmcnt counts exact.
#define LLCLD(dst, ptr) \
  asm volatile("global_load_dwordx4 %0, %1, off sc0 sc1" \
               : "=v"(dst) : "v"(ptr))
#define LLCLD4(dst, ptr) \
  asm volatile("global_load_dword %0, %1, off sc0 sc1" \
               : "=v"(dst) : "v"(ptr))
#define LLCLD8(dst, ptr) \
  asm volatile("global_load_dwordx2 %0, %1, off sc0 sc1" \
               : "=v"(dst) : "v"(ptr))
#define PLLD(dst, ptr) \
  asm volatile("global_load_dwordx4 %0, %1, off" \
               : "=v"(dst) : "v"(ptr))

#define WAITC(n)                                              \
  asm volatile("s_waitcnt vmcnt(" #n ")" ::: "memory");       \
  __builtin_amdgcn_sched_barrier(0)

// Flush-free grid barriers (one atomicAdd + poll per block).
__device__ __forceinline__ void gbar(unsigned int* bar, int t) {
  __syncthreads();
  if (threadIdx.x == 0) {
    unsigned int* cnt = bar + t * 32;
    __hip_atomic_fetch_add(cnt, 1u, __ATOMIC_RELAXED,
                           __HIP_MEMORY_SCOPE_AGENT);
    while (__hip_atomic_load(cnt, __ATOMIC_RELAXED,
                             __HIP_MEMORY_SCOPE_AGENT) < (unsigned)ENCB)
      __builtin_amdgcn_s_sleep(2);
  }
  __syncthreads();
}
__device__ __forceinline__ void gbar2(unsigned int* cell) {
  __syncthreads();
  if (threadIdx.x == 0) {
    __hip_atomic_fetch_add(cell, 1u, __ATOMIC_RELAXED,
                           __HIP_MEMORY_SCOPE_AGENT);
    while (__hip_atomic_load(cell, __ATOMIC_RELAXED,
                             __HIP_MEMORY_SCOPE_AGENT) < (unsigned)DECB)
      __builtin_amdgcn_s_sleep(2);
  }
  __syncthreads();
}

// ---------------------------------------------------------------------------
// conv front (proven round 1)
// ---------------------------------------------------------------------------
__global__ __launch_bounds__(128) void conv_front(
    const float* __restrict__ x,
    const float* __restrict__ w1, const float* __restrict__ b1,
    const float* __restrict__ w2, const float* __restrict__ b2,
    const float* __restrict__ w3, const float* __restrict__ b3,
    float* __restrict__ lstm_in)
{
  int b = blockIdx.x;
  int t = threadIdx.x;
  __shared__ float d[128][36];
  __shared__ float h1[128][34];
  __shared__ float h2[128][32];

  const float* xr = x + (size_t)(b * NL + t) * 48;
  #pragma unroll
  for (int f = 0; f < 36; ++f) d[t][f] = xr[f];
  __syncthreads();

  float acc[34];
  {
    float bias = b1[t];
    #pragma unroll
    for (int w = 0; w < 34; ++w) acc[w] = bias;
  }
  const float* wr = w1 + t * 384;
  for (int ci = 0; ci < 128; ++ci) {
    float row[36];
    #pragma unroll
    for (int f = 0; f < 36; ++f) row[f] = d[ci][f];
    float wa = wr[ci * 3 + 0], wb = wr[ci * 3 + 1], wc = wr[ci * 3 + 2];
    #pragma unroll
    for (int w = 0; w < 34; ++w)
      acc[w] += row[w] * wa + row[w + 1] * wb + row[w + 2] * wc;
  }
  #pragma unroll
  for (int w = 0; w < 34; ++w) {
    float z = acc[w];
    h1[t][w] = (z > 20.0f) ? z : log1pf(__expf(z));
  }
  __syncthreads();

  float acc2[32];
  {
    float bias = b2[t];
    #pragma unroll
    for (int w = 0; w < 32; ++w) acc2[w] = bias;
  }
  const float* wr2 = w2 + t * 384;
  for (int ci = 0; ci < 128; ++ci) {
    float row[34];
    #pragma unroll
    for (int f = 0; f < 34; ++f) row[f] = h1[ci][f];
    float wa = wr2[ci * 3 + 0], wb = wr2[ci * 3 + 1], wc = wr2[ci * 3 + 2];
    #pragma unroll
    for (int w = 0; w < 32; ++w)
      acc2[w] += row[w] * wa + row[w + 1] * wb + row[w + 2] * wc;
  }
  #pragma unroll
  for (int w = 0; w < 32; ++w) h2[t][w] = fmaxf(acc2[w], 0.0f);
  __syncthreads();

  float* outr = lstm_in + (size_t)(b * NL + t) * 18;
  #pragma unroll
  for (int e = 0; e < 6; ++e) {
    float s = b3[e];
    #pragma unroll
    for (int f = 0; f < 32; ++f) s += h2[t][f] * w3[e * 32 + f];
    outr[e] = s;
  }
  #pragma unroll
  for (int j = 0; j < 12; ++j) outr[6 + j] = xr[36 + j];
}

// ---------------------------------------------------------------------------
// Fragment-order transforms (4-column variant).
// ---------------------------------------------------------------------------
__global__ void frag_w4(const float* __restrict__ src, int K, int kshift,
                        unsigned short* __restrict__ hi,
                        unsigned short* __restrict__ lo, int ngroups)
{
  int o = blockIdx.x * 256 + threadIdx.x;
  if (o >= ngroups) return;
  int lane = o & 63;
  int ki = (o >> 6) & ((1 << kshift) - 1);
  int t2 = o >> (6 + kshift);
  int l15 = lane & 15, q = lane >> 4;
  int grow = (l15 >> 2) * 1024 + t2 * 4 + (l15 & 3);
  const float* s = src + (size_t)grow * K + ki * 32 + q * 8;
  unsigned short hv[8], lv[8];
  #pragma unroll
  for (int j = 0; j < 8; ++j) {
    float v = s[j];
    hv[j] = f2bf(v);
    lv[j] = f2bf(v - bf2f(hv[j]));
  }
  size_t e = (size_t)o * 8;
  *(ushort4*)(hi + e) = make_ushort4(hv[0], hv[1], hv[2], hv[3]);
  *(ushort4*)(hi + e + 4) = make_ushort4(hv[4], hv[5], hv[6], hv[7]);
  *(ushort4*)(lo + e) = make_ushort4(lv[0], lv[1], lv[2], lv[3]);
  *(ushort4*)(lo + e + 4) = make_ushort4(lv[4], lv[5], lv[6], lv[7]);
}

__global__ void frag_wqk(const float* __restrict__ wq,
                         const float* __restrict__ wk,
                         unsigned short* __restrict__ hi,
                         unsigned short* __restrict__ lo)
{
  int o = blockIdx.x * 256 + threadIdx.x;
  if (o >= 65536) return;
  int lane = o & 63;
  int ki = (o >> 6) & 31;
  int ntile = o >> 11;
  int l15 = lane & 15, q = lane >> 4;
  int row = ntile * 16 + l15;
  int k = ki * 32 + q * 8;
  const float* s = (row < 256) ? (wq + (size_t)row * 1024 + k)
                               : (wk + (size_t)(row - 256) * 1024 + k);
  unsigned short hv[8], lv[8];
  #pragma unroll
  for (int j = 0; j < 8; ++j) {
    float v = s[j];
    hv[j] = f2bf(v);
    lv[j] = f2bf(v - bf2f(hv[j]));
  }
  size_t e = (size_t)o * 8;
  *(ushort4*)(hi + e) = make_ushort4(hv[0], hv[1], hv[2], hv[3]);
  *(ushort4*)(hi + e + 4) = make_ushort4(hv[4], hv[5], hv[6], hv[7]);
  *(ushort4*)(lo + e) = make_ushort4(lv[0], lv[1], lv[2], lv[3]);
  *(ushort4*)(lo + e + 4) = make_ushort4(lv[4], lv[5], lv[6], lv[7]);
}

__global__ void frag_wx4(const float* __restrict__ wih,
                         unsigned short* __restrict__ hi,
                         unsigned short* __restrict__ lo)
{
  int o = blockIdx.x * 256 + threadIdx.x;
  if (o >= 16384) return;
  int lane = o & 63;
  int t2 = o >> 6;
  int l15 = lane & 15, q = lane >> 4;
  int grow = (l15 >> 2) * 1024 + t2 * 4 + (l15 & 3);
  unsigned short hv[8], lv[8];
  #pragma unroll
  for (int j = 0; j < 8; ++j) {
    int k = q * 8 + j;
    float v = (k < 18) ? wih[(size_t)grow * 18 + k] : 0.0f;
    hv[j] = f2bf(v);
    lv[j] = f2bf(v - bf2f(hv[j]));
  }
  size_t e = (size_t)o * 8;
  *(ushort4*)(hi + e) = make_ushort4(hv[0], hv[1], hv[2], hv[3]);
  *(ushort4*)(hi + e + 4) = make_ushort4(hv[4], hv[5], hv[6], hv[7]);
  *(ushort4*)(lo + e) = make_ushort4(lv[0], lv[1], lv[2], lv[3]);
  *(ushort4*)(lo + e + 4) = make_ushort4(lv[4], lv[5], lv[6], lv[7]);
}

__global__ void frag_xs(const float* __restrict__ lstm_in,
                        unsigned short* __restrict__ hi,
                        unsigned short* __restrict__ lo)
{
  int o = blockIdx.x * 256 + threadIdx.x;
  if (o >= 65536) return;
  int lane = o & 63;
  int btile = (o >> 6) & 7;
  int t = o >> 9;
  int l15 = lane & 15, q = lane >> 4;
  int b = btile * 16 + l15;
  unsigned short hv[8], lv[8];
  #pragma unroll
  for (int j = 0; j < 8; ++j) {
    int k = q * 8 + j;
    float v = (k < 18) ? lstm_in[(size_t)(b * NL + t) * 18 + k] : 0.0f;
    hv[j] = f2bf(v);
    lv[j] = f2bf(v - bf2f(hv[j]));
  }
  size_t e = (size_t)o * 8;
  *(ushort4*)(hi + e) = make_ushort4(hv[0], hv[1], hv[2], hv[3]);
  *(ushort4*)(hi + e + 4) = make_ushort4(hv[4], hv[5], hv[6], hv[7]);
  *(ushort4*)(lo + e) = make_ushort4(lv[0], lv[1], lv[2], lv[3]);
  *(ushort4*)(lo + e + 4) = make_ushort4(lv[4], lv[5], lv[6], lv[7]);
}

__global__ void init_all(float* __restrict__ c,
                         unsigned short* __restrict__ hhi0,
                         unsigned short* __restrict__ hlo0,
                         float* __restrict__ out,
                         unsigned int* __restrict__ bar) {
  int i = blockIdx.x * 256 + threadIdx.x;
  if (i < NB * NH) { c[i] = 0.0f; hhi0[i] = 0; hlo0[i] = 0; }
  if (i < NB * NT) out[i] = 0.0f;
  if (i < 8192) bar[i] = 0;
}

__global__ void zero_dbar(unsigned int* __restrict__ dbar) {
  dbar[threadIdx.x] = 0;
}

// ---------------------------------------------------------------------------
// enc_all (unchanged from round 13 -- 11.7us/step proven)
// ---------------------------------------------------------------------------
__global__ __launch_bounds__(512) void enc_all(
    unsigned short* __restrict__ hfA_hi, unsigned short* __restrict__ hfA_lo,
    unsigned short* __restrict__ hfB_hi, unsigned short* __restrict__ hfB_lo,
    const unsigned short* __restrict__ Wf_hi,
    const unsigned short* __restrict__ Wf_lo,
    const unsigned short* __restrict__ Wxf_hi,
    const unsigned short* __restrict__ Wxf_lo,
    const unsigned short* __restrict__ xsf_hi,
    const unsigned short* __restrict__ xsf_lo,
    const float* __restrict__ encb,
    float* __restrict__ c,
    short* __restrict__ buf,
    unsigned int* __restrict__ bar)
{
  __shared__ __align__(16) unsigned short SWh[32768];
  __shared__ __align__(16) unsigned short SWl[32768];
  __shared__ __align__(16) unsigned short SXh[1024];
  __shared__ __align__(16) unsigned short SXl[1024];
  __shared__ float G[128][33];

  int tid = threadIdx.x, bx = blockIdx.x;
  int w8 = tid >> 6, lane = tid & 63;
  int l15 = lane & 15, q4 = (lane >> 4) * 4;
  int ab = w8;
  int lane8 = lane * 8;
  size_t abl8 = (size_t)ab * 512 + lane8;

  {
    const unsigned short* gh = Wf_hi + (size_t)(bx * 2) * 16384;
    const unsigned short* gl = Wf_lo + (size_t)(bx * 2) * 16384;
    for (int i = tid * 8; i < 32768; i += 4096) {
      *(bf16x8*)(SWh + i) = *(const bf16x8*)(gh + i);
      *(bf16x8*)(SWl + i) = *(const bf16x8*)(gl + i);
    }
    if (tid < 128) {
      *(bf16x8*)(SXh + tid * 8) =
          *(const bf16x8*)(Wxf_hi + (size_t)(bx * 2) * 512 + tid * 8);
      *(bf16x8*)(SXl + tid * 8) =
          *(const bf16x8*)(Wxf_lo + (size_t)(bx * 2) * 512 + tid * 8);
    }
  }

  int eb = tid >> 1;
  int lt = tid & 1;
  int ekc = bx * 8 + lt * 4;
  float bias[4][4];
  #pragma unroll
  for (int q = 0; q < 4; ++q)
    #pragma unroll
    for (int j = 0; j < 4; ++j)
      bias[q][j] = encb[q * NH + ekc + j];
  float4 creg = make_float4(0.f, 0.f, 0.f, 0.f);
  int eki = ekc >> 5, eqq = (ekc >> 3) & 3, ej8 = ekc & 7;
  size_t efo = (size_t)eki * 4096 + (eb >> 4) * 512 +
               ((eb & 15) + 16 * eqq) * 8 + ej8;
  __syncthreads();

#define COMP1(kk) {                                                      \
    bf16x8 bh0 = *(const bf16x8*)(SWh + (kk) * 512 + lane8);             \
    bf16x8 bl0 = *(const bf16x8*)(SWl + (kk) * 512 + lane8);             \
    bf16x8 bh1 = *(const bf16x8*)(SWh + 16384 + (kk) * 512 + lane8);     \
    bf16x8 bl1 = *(const bf16x8*)(SWl + 16384 + (kk) * 512 + lane8);     \
    acc0 = MFMA(xh[kk], bh0, acc0); acc0 = MFMA(xl[kk], bh0, acc0);      \
    acc0 = MFMA(xh[kk], bl0, acc0);                                      \
    acc1 = MFMA(xh[kk], bh1, acc1); acc1 = MFMA(xl[kk], bh1, acc1);      \
    acc1 = MFMA(xh[kk], bl1, acc1); }

#define ISSUE(j) {                                                       \
    const unsigned short* p0 = hih + (size_t)(2 * (j)) * 4096 + abl8;    \
    const unsigned short* p1 = hil + (size_t)(2 * (j)) * 4096 + abl8;    \
    LLCLD(xh[2 * (j)], p0);                                              \
    LLCLD(xl[2 * (j)], p1);                                              \
    LLCLD(xh[2 * (j) + 1], p0 + 4096);                                   \
    LLCLD(xl[2 * (j) + 1], p1 + 4096); }

  for (int t = 0; t < NL; ++t) {
    const unsigned short* hih = (t & 1) ? hfB_hi : hfA_hi;
    const unsigned short* hil = (t & 1) ? hfB_lo : hfA_lo;
    unsigned short* hoh = (t & 1) ? hfA_hi : hfB_hi;
    unsigned short* hol = (t & 1) ? hfA_lo : hfB_lo;

    f32x4 acc0 = {0,0,0,0}, acc1 = {0,0,0,0};

    {
      size_t xo = ((size_t)t * 8 + ab) * 512 + lane8;
      bf16x8 sh = *(const bf16x8*)(xsf_hi + xo);
      bf16x8 sl = *(const bf16x8*)(xsf_lo + xo);
      bf16x8 y0h = *(const bf16x8*)(SXh + lane8);
      bf16x8 y0l = *(const bf16x8*)(SXl + lane8);
      bf16x8 y1h = *(const bf16x8*)(SXh + 512 + lane8);
      bf16x8 y1l = *(const bf16x8*)(SXl + 512 + lane8);
      acc0 = MFMA(sh, y0h, acc0); acc0 = MFMA(sl, y0h, acc0);
      acc0 = MFMA(sh, y0l, acc0);
      acc1 = MFMA(sh, y1h, acc1); acc1 = MFMA(sl, y1h, acc1);
      acc1 = MFMA(sh, y1l, acc1);
    }
    WAITC(0);

    bf16x8 xh[32], xl[32];
    ISSUE(0); ISSUE(1); ISSUE(2); ISSUE(3);
    WAITC(12); ISSUE(4);  COMP1(0);  COMP1(1);
    WAITC(12); ISSUE(5);  COMP1(2);  COMP1(3);
    WAITC(12); ISSUE(6);  COMP1(4);  COMP1(5);
    WAITC(12); ISSUE(7);  COMP1(6);  COMP1(7);
    WAITC(12); ISSUE(8);  COMP1(8);  COMP1(9);
    WAITC(12); ISSUE(9);  COMP1(10); COMP1(11);
    WAITC(12); ISSUE(10); COMP1(12); COMP1(13);
    WAITC(12); ISSUE(11); COMP1(14); COMP1(15);
    WAITC(12); ISSUE(12); COMP1(16); COMP1(17);
    WAITC(12); ISSUE(13); COMP1(18); COMP1(19);
    WAITC(12); ISSUE(14); COMP1(20); COMP1(21);
    WAITC(12); ISSUE(15); COMP1(22); COMP1(23);
    WAITC(12); COMP1(24); COMP1(25);
    WAITC(8);  COMP1(26); COMP1(27);
    WAITC(4);  COMP1(28); COMP1(29);
    WAITC(0);  COMP1(30); COMP1(31);

    #pragma unroll
    for (int r = 0; r < 4; ++r) {
      G[ab * 16 + q4 + r][l15]      = acc0[r];
      G[ab * 16 + q4 + r][16 + l15] = acc1[r];
    }
    __syncthreads();

    if (tid < 256) {
      float rh[4];
      float* cp = &creg.x;
      #pragma unroll
      for (int j = 0; j < 4; ++j) {
        float gate[4];
        #pragma unroll
        for (int q = 0; q < 4; ++q)
          gate[q] = G[eb][lt * 16 + q * 4 + j] + bias[q][j];
        float cn = sig_f(gate[1]) * cp[j] + sig_f(gate[0]) * tanh_f(gate[2]);
        float hn = sig_f(gate[3]) * tanh_f(cn);
        cp[j] = cn; rh[j] = hn;
      }
      unsigned short hh[4], hl[4];
      short hq[4];
      #pragma unroll
      for (int j = 0; j < 4; ++j) {
        hh[j] = f2bf(rh[j]);
        hl[j] = f2bf(rh[j] - bf2f(hh[j]));
        hq[j] = f2i16(rh[j]);
      }
      ast8(hoh + efo, hh[0], hh[1], hh[2], hh[3]);
      ast8(hol + efo, hl[0], hl[1], hl[2], hl[3]);
      *(short4*)(buf + (size_t)(eb * NM + t) * NH + ekc) =
          make_short4(hq[0], hq[1], hq[2], hq[3]);
    }
    if (t < NL - 1) gbar(bar, t);
  }
  if (tid < 256)
    *(float4*)(c + (size_t)eb * NH + ekc) = creg;
#undef COMP1
#undef ISSUE
}

// ---------------------------------------------------------------------------
// dec_prep: read final h (frag) + c (row-major) -> q frag rows 2b / 2b+1.
// ---------------------------------------------------------------------------
__global__ __launch_bounds__(256) void dec_prep(
    const unsigned short* __restrict__ hf_hi,
    const unsigned short* __restrict__ hf_lo,
    const float* __restrict__ c,
    unsigned short* __restrict__ qhi, unsigned short* __restrict__ qlo)
{
  int b = blockIdx.x;
  int j4 = threadIdx.x * 4;
  int ki = j4 >> 5, qq = (j4 >> 3) & 3, j8 = j4 & 7;
  size_t fh = (size_t)ki * 4096 + (b >> 4) * 512 + ((b & 15) + 16 * qq) * 8 + j8;
  ushort4 hv = *(const ushort4*)(hf_hi + fh);
  ushort4 lv = *(const ushort4*)(hf_lo + fh);
  float4 cv = *(const float4*)(c + (size_t)b * NH + j4);
  unsigned short ch[4], cl[4];
  float cf[4] = {cv.x, cv.y, cv.z, cv.w};
  #pragma unroll
  for (int k = 0; k < 4; ++k) {
    ch[k] = f2bf(cf[k]); cl[k] = f2bf(cf[k] - bf2f(ch[k]));
  }
  int rt = (2 * b) >> 4;
  int rl = ((2 * b) & 15) + 16 * qq;
  size_t fq = (size_t)ki * 8192 + rt * 512 + rl * 8 + j8;
  *(ushort4*)(qhi + fq) = hv;
  *(ushort4*)(qlo + fq) = lv;
  *(ushort4*)(qhi + fq + 8) = make_ushort4(ch[0], ch[1], ch[2], ch[3]);
  *(ushort4*)(qlo + fq + 8) = make_ushort4(cl[0], cl[1], cl[2], cl[3]);
}

// ---------------------------------------------------------------------------
// Bulk kp: kp = buf(i16, row-major) @ Wk^T (frag B, 2-term). grid(302,4).
// ---------------------------------------------------------------------------
__global__ __launch_bounds__(256) void gemm_kp(
    const short* __restrict__ A,
    const unsigned short* __restrict__ Bhi,
    const unsigned short* __restrict__ Blo,
    unsigned short* __restrict__ C)
{
  int tid = threadIdx.x;
  int w = tid >> 6, lane = tid & 63;
  int l15 = lane & 15, q8 = (lane >> 4) * 8, q4 = (lane >> 4) * 4;
  size_t m0 = (size_t)blockIdx.x * 64;
  int n0 = blockIdx.y * 64 + w * 16;
  int ntile = 16 + blockIdx.y * 4 + w;

  const unsigned short* Bh = Bhi + (size_t)ntile * 16384 + lane * 8;
  const unsigned short* Bl = Blo + (size_t)ntile * 16384 + lane * 8;
  f32x4 acc[4] = {{0,0,0,0},{0,0,0,0},{0,0,0,0},{0,0,0,0}};
  for (int ki = 0; ki < 32; ++ki) {
    int ko = ki * 32 + q8;
    size_t bo = (size_t)ki * 512;
    bf16x8 bh = *(const bf16x8*)(Bh + bo);
    bf16x8 bl = *(const bf16x8*)(Bl + bo);
    #pragma unroll
    for (int i = 0; i < 4; ++i) {
      s16x8 av = *(const s16x8*)(A + (m0 + 16 * i + l15) * (size_t)NH + ko);
      bf16x8 ah;
      #pragma unroll
      for (int k = 0; k < 8; ++k)
        ah[k] = (short)f2bf((float)av[k] * I16_INV);
      acc[i] = MFMA(ah, bh, acc[i]);
      acc[i] = MFMA(ah, bl, acc[i]);
    }
  }
  #pragma unroll
  for (int i = 0; i < 4; ++i)
    #pragma unroll
    for (int r = 0; r < 4; ++r)
      C[(m0 + 16 * i + q4 + r) * NA + n0 + l15] = f2bf(acc[i][r]);
}

// ---------------------------------------------------------------------------
// dec_all v4: 256 blocks x 512 thr, 4 gate-cols/block, small-live pipelines.
// ---------------------------------------------------------------------------
__global__ __launch_bounds__(512) void dec_all(
    unsigned short* __restrict__ Xfh, unsigned short* __restrict__ Xfl,
    unsigned short* __restrict__ qAh, unsigned short* __restrict__ qAl,
    unsigned short* __restrict__ qBh, unsigned short* __restrict__ qBl,
    const unsigned short* __restrict__ Wqh, const unsigned short* __restrict__ Wql,
    const unsigned short* __restrict__ WdxHg, const unsigned short* __restrict__ WdxLg,
    const unsigned short* __restrict__ WdhHg, const unsigned short* __restrict__ WdhLg,
    const float* __restrict__ decb, const float* __restrict__ cin,
    short* __restrict__ buf, unsigned short* __restrict__ kp,
    float* __restrict__ qkout, const float* __restrict__ Wv,
    const float* __restrict__ out_w, const float* __restrict__ out_b,
    float* __restrict__ out, unsigned int* __restrict__ dbar)
{
  __shared__ __align__(16) unsigned short SDh[16384];   // Wdh tile (32KB)
  __shared__ __align__(16) unsigned short SDl[16384];
  __shared__ float G[128][17];
  __shared__ float PG[8][256];
  __shared__ float sWv[256], q0s[256], q1s[256], kNs[256];
  __shared__ float sc2[2][NM + 1];
  __shared__ float w0s[NM + 1], w1s[NM + 1];

  int tid = threadIdx.x, bx = blockIdx.x;
  int w8 = tid >> 6, lane = tid & 63;
  int l15 = lane & 15, q4 = (lane >> 4) * 4;
  int ab = w8;
  int lane8 = lane * 8;
  int b = bx;   // batch for phase B (bx < 128 only)

  // stage Wdh tile (64 KB) into LDS once
  {
    const unsigned short* gh = WdhHg + (size_t)bx * 16384;
    const unsigned short* gl = WdhLg + (size_t)bx * 16384;
    for (int i = tid * 8; i < 16384; i += 4096) {
      *(bf16x8*)(SDh + i) = *(const bf16x8*)(gh + i);
      *(bf16x8*)(SDl + i) = *(const bf16x8*)(gl + i);
    }
  }
  if (tid < 256) sWv[tid] = Wv[tid];

  // epilogue state: thread tid<128 owns batch tid, cols bx*4..bx*4+3
  int kc = bx * 4;
  float4 creg = make_float4(0.f, 0.f, 0.f, 0.f);
  if (tid < 128)
    creg = *(const float4*)(cin + (size_t)tid * NH + kc);
  int eki = kc >> 5, eqq = (kc >> 3) & 3, ej8 = kc & 7;
  __syncthreads();

  for (int t = 0; t < NT; ++t) {
    const unsigned short* qih = (t & 1) ? qBh : qAh;
    const unsigned short* qil = (t & 1) ? qBl : qAl;
    unsigned short* qoh = (t & 1) ? qAh : qBh;
    unsigned short* qol = (t & 1) ? qAl : qBl;
    int Mt = NL + t;

    // ====== phase A: qkout = q @ Wqk^T, K-split over 8 waves ======
    {
      int tile01 = w8 & 1;
      int kq = w8 >> 1;                 // K-quarter 0..3 (8 ki each)
      int g = bx * 2 + tile01;
      int mtile = g >> 5, ntile = g & 31;
      const unsigned short* Ah = qih + (size_t)mtile * 512 + lane8;
      const unsigned short* Al = qil + (size_t)mtile * 512 + lane8;
      const unsigned short* Bh = Wqh + (size_t)ntile * 16384 + lane8;
      const unsigned short* Bl = Wql + (size_t)ntile * 16384 + lane8;
      int k0 = kq * 8;
      f32x4 acc = {0, 0, 0, 0};
      bf16x8 axh[4], axl[4], awh[4], awl[4];
#define AISS(J) { _Pragma("unroll") for (int i_ = 0; i_ < 2; ++i_) {     \
      size_t ko = (size_t)(k0 + (J) * 2 + i_); int w_ = ((J) & 1) * 2 + i_; \
      LLCLD(axh[w_], Ah + ko * 8192); LLCLD(axl[w_], Al + ko * 8192);    \
      PLLD(awh[w_], Bh + ko * 512);   PLLD(awl[w_], Bl + ko * 512); } }
      AISS(0); AISS(1);
      #pragma unroll
      for (int jj = 0; jj < 4; ++jj) {
        if (jj < 3) { WAITC(8); } else { WAITC(0); }
        #pragma unroll
        for (int i_ = 0; i_ < 2; ++i_) {
          int w_ = (jj & 1) * 2 + i_;
          acc = MFMA(axh[w_], awh[w_], acc);
          acc = MFMA(axl[w_], awh[w_], acc);
          acc = MFMA(axh[w_], awl[w_], acc);
        }
        if (jj < 2) { AISS(jj + 2); }
      }
#undef AISS
      #pragma unroll
      for (int r = 0; r < 4; ++r)
        PG[w8][(q4 + r) * 16 + l15] = acc[r];
    }
    __syncthreads();
    {
      int tile01 = tid >> 8;
      int rc = tid & 255;
      float v = PG[tile01][rc] + PG[2 + tile01][rc] +
                PG[4 + tile01][rc] + PG[6 + tile01][rc];
      int g = bx * 2 + tile01;
      int mtile = g >> 5, ntile = g & 31;
      int row = rc >> 4, col = rc & 15;
      astf(qkout + (size_t)(mtile * 16 + row) * 512 + ntile * 16 + col, v);
    }
    gbar2(dbar + t * 3 + 0);

    // ================= phase B: attention (blocks 0..127) =================
    if (bx < NB) {
      if (tid < 256) {
        unsigned int u0, u1, u2;
        LLCLD4(u0, (const float*)qkout + (size_t)(2 * b) * 512 + tid);
        LLCLD4(u1, (const float*)qkout + (size_t)(2 * b + 1) * 512 + tid);
        LLCLD4(u2, (const float*)qkout + (size_t)(2 * b) * 512 + 256 + tid);
        WAITC(0);
        q0s[tid] = __uint_as_float(u0);
        q1s[tid] = __uint_as_float(u1);
        float kn = __uint_as_float(u2);
        kNs[tid] = kn;
        if (t < NT - 1)   // row 150 hosts dbar; dead write skipped
          kp[((size_t)(b * NM) + (NL - 1 + t)) * NA + tid] = f2bf(kn);
      }
      __syncthreads();

      for (int idx = tid; idx < 2 * Mt; idx += 512) {
        int m = idx >> 1, n = idx & 1;
        const float* q = n ? q1s : q0s;
        float s = 0.0f;
        if (m == Mt - 1) {
          for (int a = 0; a < NA; ++a) s += tanh_f(q[a] + kNs[a]) * sWv[a];
        } else {
          const unsigned short* kpr = kp + ((size_t)(b * NM) + m) * NA;
          for (int a = 0; a < NA; a += 4) {
            ushort4 kv = *(const ushort4*)(kpr + a);
            s += tanh_f(q[a + 0] + bf2f(kv.x)) * sWv[a + 0];
            s += tanh_f(q[a + 1] + bf2f(kv.y)) * sWv[a + 1];
            s += tanh_f(q[a + 2] + bf2f(kv.z)) * sWv[a + 2];
            s += tanh_f(q[a + 3] + bf2f(kv.w)) * sWv[a + 3];
          }
        }
        sc2[n][m] = s;
      }
      __syncthreads();
      for (int m = tid; m < Mt; m += 512) {
        float s0 = sc2[0][m], s1 = sc2[1][m];
        float mx = fmaxf(s0, s1);
        float e0 = __expf(s0 - mx), e1 = __expf(s1 - mx);
        float inv = 1.0f / (e0 + e1);
        w0s[m] = e0 * inv;
        w1s[m] = e1 * inv;
      }
      for (int m = Mt + tid; m < NM; m += 512) { w0s[m] = 0.f; w1s[m] = 0.f; }
      __syncthreads();

      // PV: all 512 threads (tid<256 -> head 0, tid>=256 -> head 1)
      {
        int n = tid >> 8;
        int cc = (tid & 255) * 4;
        const float* ws = n ? w1s : w0s;
        float4 a = {0, 0, 0, 0};
        const short* bb = buf + ((size_t)b * NM) * NH + cc;
        for (int m = 0; m < NL; ++m) {
          short4 v = *(const short4*)(bb + (size_t)m * NH);
          float w = ws[m];
          a.x += (float)v.x * I16_INV * w; a.y += (float)v.y * I16_INV * w;
          a.z += (float)v.z * I16_INV * w; a.w += (float)v.w * I16_INV * w;
        }
        {
          union U8 { unsigned long long u; short4 s; } tv[23];
          #pragma unroll
          for (int m = 0; m < 23; ++m)
            LLCLD8(tv[m].u, bb + (size_t)(NL + m) * NH);
          WAITC(0);
          #pragma unroll
          for (int m = 0; m < 23; ++m) {
            short4 v = tv[m].s;
            float w = ws[NL + m];
            a.x += (float)v.x * I16_INV * w; a.y += (float)v.y * I16_INV * w;
            a.z += (float)v.z * I16_INV * w; a.w += (float)v.w * I16_INV * w;
          }
        }
        float av[4] = {a.x, a.y, a.z, a.w};
        unsigned short h4[4], l4[4];
        #pragma unroll
        for (int k = 0; k < 4; ++k) {
          h4[k] = f2bf(av[k]); l4[k] = f2bf(av[k] - bf2f(h4[k]));
        }
        int ke = n * 1024 + cc;
        size_t fo = (size_t)(ke >> 5) * 4096 + (b >> 4) * 512 +
                    ((b & 15) + 16 * ((ke >> 3) & 3)) * 8 + (ke & 7);
        ast8(Xfh + fo, h4[0], h4[1], h4[2], h4[3]);
        ast8(Xfl + fo, l4[0], l4[1], l4[2], l4[3]);
      }
    }
    gbar2(dbar + t * 3 + 1);

    // ================= phase C: LSTM (single col-tile per block) ==========
    {
      f32x4 acc = {0, 0, 0, 0};
      // ctx part (64 ki): 2ki windows, 3-deep (24 live bf16x8)
      {
        const unsigned short* XAh = Xfh + (size_t)ab * 512 + lane8;
        const unsigned short* XAl = Xfl + (size_t)ab * 512 + lane8;
        const unsigned short* WXH = WdxHg + (size_t)bx * 32768 + lane8;
        const unsigned short* WXL = WdxLg + (size_t)bx * 32768 + lane8;
        bf16x8 cxh[6], cxl[6], cwh[6], cwl[6];
#define CISS(J) { _Pragma("unroll") for (int i_ = 0; i_ < 2; ++i_) {       \
        size_t ko = (size_t)((J) * 2 + i_); int w_ = ((J) % 3) * 2 + i_;   \
        LLCLD(cxh[w_], XAh + ko * 4096); LLCLD(cxl[w_], XAl + ko * 4096);  \
        PLLD(cwh[w_], WXH + ko * 512);   PLLD(cwl[w_], WXL + ko * 512); } }
        CISS(0); CISS(1); CISS(2);
        #pragma unroll
        for (int jj = 0; jj < 32; ++jj) {
          if (jj <= 29)      { WAITC(16); }
          else if (jj == 30) { WAITC(8); }
          else               { WAITC(0); }
          #pragma unroll
          for (int i_ = 0; i_ < 2; ++i_) {
            int w_ = (jj % 3) * 2 + i_;
            acc = MFMA(cxh[w_], cwh[w_], acc);
            acc = MFMA(cxl[w_], cwh[w_], acc);
            acc = MFMA(cxh[w_], cwl[w_], acc);
          }
          if (jj <= 28) { CISS(jj + 3); }
        }
#undef CISS
      }
      // h-part (32 ki): A from q frag (LLC), 4ki windows 2-deep; W from LDS
      {
        const unsigned short* QAh = qih +
            (size_t)(2 * ab + (l15 >> 3)) * 512 +
            (2 * (l15 & 7) + 16 * (lane >> 4)) * 8;
        const unsigned short* QAl = qil +
            (size_t)(2 * ab + (l15 >> 3)) * 512 +
            (2 * (l15 & 7) + 16 * (lane >> 4)) * 8;
        bf16x8 axh[8], axl[8];
#define HISS(P, J) { _Pragma("unroll") for (int i_ = 0; i_ < 4; ++i_) {    \
        LLCLD(axh[(P) * 4 + i_], QAh + (size_t)((J) * 4 + i_) * 8192);     \
        LLCLD(axl[(P) * 4 + i_], QAl + (size_t)((J) * 4 + i_) * 8192); } }
        HISS(0, 0);
        #pragma unroll
        for (int j = 0; j < 8; ++j) {
          if (j < 7) { HISS((j + 1) & 1, j + 1); WAITC(8); }
          else { WAITC(0); }
          #pragma unroll
          for (int i_ = 0; i_ < 4; ++i_) {
            int bo = (j * 4 + i_) * 512 + lane8;
            bf16x8 bh0 = *(const bf16x8*)(SDh + bo);
            bf16x8 bl0 = *(const bf16x8*)(SDl + bo);
            bf16x8 xh_ = axh[(j & 1) * 4 + i_];
            bf16x8 xl_ = axl[(j & 1) * 4 + i_];
            acc = MFMA(xh_, bh0, acc); acc = MFMA(xl_, bh0, acc);
            acc = MFMA(xh_, bl0, acc);
          }
        }
#undef HISS
      }
      #pragma unroll
      for (int r = 0; r < 4; ++r)
        G[ab * 16 + q4 + r][l15] = acc[r];
    }
    __syncthreads();

    if (tid < 128) {
      int eb = tid;
      float rh[4], rc[4];
      float* cp = &creg.x;
      #pragma unroll
      for (int j = 0; j < 4; ++j) {
        float gate[4];
        #pragma unroll
        for (int q = 0; q < 4; ++q)
          gate[q] = G[eb][q * 4 + j] + decb[q * NH + kc + j];
        float cn = sig_f(gate[1]) * cp[j] + sig_f(gate[0]) * tanh_f(gate[2]);
        float hn = sig_f(gate[3]) * tanh_f(cn);
        cp[j] = cn; rc[j] = cn; rh[j] = hn;
      }
      float py = 0.0f;
      #pragma unroll
      for (int j = 0; j < 4; ++j) py += rh[j] * out_w[kc + j];
      if (bx == 0) py += out_b[0];
      atomicAdd(&out[eb * NT + t], py);

      if (t < NT - 1) {
        unsigned short hh[4], hl[4], ch[4], cl[4];
        short hq[4];
        #pragma unroll
        for (int j = 0; j < 4; ++j) {
          hh[j] = f2bf(rh[j]); hl[j] = f2bf(rh[j] - bf2f(hh[j]));
          ch[j] = f2bf(rc[j]); cl[j] = f2bf(rc[j] - bf2f(ch[j]));
          hq[j] = f2i16(rh[j]);
        }
        ast8((unsigned short*)(buf + (size_t)(eb * NM + NL + t) * NH + kc),
             (unsigned short)hq[0], (unsigned short)hq[1],
             (unsigned short)hq[2], (unsigned short)hq[3]);
        int ert = (2 * eb) >> 4;
        int erl = ((2 * eb) & 15) + 16 * eqq;
        size_t fq = (size_t)eki * 8192 + ert * 512 + erl * 8 + ej8;
        ast8(qoh + fq, hh[0], hh[1], hh[2], hh[3]);
        ast8(qol + fq, hl[0], hl[1], hl[2], hl[3]);
        ast8(qoh + fq + 8, ch[0], ch[1], ch[2], ch[3]);
        ast8(qol + fq + 8, cl[0], cl[1], cl[2], cl[3]);
      }
    }
    if (t < NT - 1) gbar2(dbar + t * 3 + 2);
  }
}

// ---------------------------------------------------------------------------
extern "C" void kernel_launch(void* const* d_in, const int* in_sizes, int n_in,
                              void* d_out, int out_size, void* d_ws, size_t ws_size,
                              hipStream_t stream) {
  const float* x       = (const float*)d_in[0];
  const float* conv1_w = (const float*)d_in[1];
  const float* conv1_b = (const float*)d_in[2];
  const float* conv2_w = (const float*)d_in[3];
  const float* conv2_b = (const float*)d_in[4];
  const float* lin3_w  = (const float*)d_in[5];
  const float* lin3_b  = (const float*)d_in[6];
  const float* enc_Wih = (const float*)d_in[7];
  const float* enc_Whh = (const float*)d_in[8];
  const float* enc_b   = (const float*)d_in[9];
  const float* attn_Wq = (const float*)d_in[10];
  const float* attn_Wk = (const float*)d_in[11];
  const float* attn_Wv = (const float*)d_in[12];
  const float* dec_Wih = (const float*)d_in[13];
  const float* dec_Whh = (const float*)d_in[14];
  const float* dec_b   = (const float*)d_in[15];
  const float* out_w   = (const float*)d_in[16];
  const float* out_b   = (const float*)d_in[17];
  float* out = (float*)d_out;

  // ---- workspace carve: identical totals to rounds 6-16 ----
  unsigned short* W = (unsigned short*)d_ws;
  short*          buf    = (short*)W;                  // 19,791,872 i16
  unsigned short* kp     = W + (size_t)19791872;       // 4,947,968
  unsigned short* qA_hi  = kp + 4947968;               // 262,144 (q frag)
  unsigned short* qA_lo  = qA_hi + 262144;
  unsigned short* qB_hi  = qA_lo + 262144;
  unsigned short* qB_lo  = qB_hi + 262144;
  unsigned short* Xf_hi  = qB_lo + 262144;             // 262,144 (ctx frag)
  unsigned short* Xf_lo  = Xf_hi + 262144;
  unsigned short* Wqkf_hi = Xf_lo + 262144;            // 524,288 (frag)
  unsigned short* Wqkf_lo = Wqkf_hi + 524288;
  unsigned short* Wdhf_hi = Wqkf_lo + 524288;          // 4,194,304 (enc Whh first)
  unsigned short* Wdhf_lo = Wdhf_hi + 4194304;
  unsigned short* Wdxf_hi = Wdhf_lo + 4194304;         // 8,388,608
  unsigned short* Wdxf_lo = Wdxf_hi + 8388608;         // 8,388,608
  float* c     = (float*)(Wdxf_lo + 8388608);          // 131,072 f
  float* qkout = c + 131072;                           // 131,072 f
  // encoder-phase overlays in Wdxf regions (dead until dec weight transform):
  unsigned short* hfA_hi = Wdxf_hi;                    // 131,072 (h frag)
  unsigned short* hfA_lo = Wdxf_hi + 131072;
  unsigned short* hfB_hi = Wdxf_hi + 262144;
  unsigned short* hfB_lo = Wdxf_hi + 393216;
  unsigned short* xsf_hi = Wdxf_hi + 524288;           // 524,288
  unsigned short* xsf_lo = xsf_hi + 524288;            // 524,288
  unsigned short* Wxf_hi = xsf_lo + 524288;            // 131,072
  unsigned short* Wxf_lo = Wxf_hi + 131072;            // 131,072
  float* lstm_in = (float*)Wdxf_lo;                    // 294,912 f
  // enc barrier: dead space inside Wdxf_lo overlay (valid pre-transform)
  unsigned int* bar = (unsigned int*)(Wdxf_lo + 1048576);
  // dec barrier: kp row 150 of batch 0 (never read; re-zeroed post-gemm_kp)
  unsigned int* dbar = (unsigned int*)(kp + (size_t)150 * NA);

  init_all<<<512, 256, 0, stream>>>(c, hfA_hi, hfA_lo, out, bar);
  conv_front<<<NB, 128, 0, stream>>>(x, conv1_w, conv1_b, conv2_w, conv2_b,
                                     lin3_w, lin3_b, lstm_in);
  frag_xs<<<256, 256, 0, stream>>>(lstm_in, xsf_hi, xsf_lo);
  frag_wx4<<<64, 256, 0, stream>>>(enc_Wih, Wxf_hi, Wxf_lo);
  frag_w4<<<2048, 256, 0, stream>>>(enc_Whh, 1024, 5, Wdhf_hi, Wdhf_lo, 524288);
  frag_wqk<<<256, 256, 0, stream>>>(attn_Wq, attn_Wk, Wqkf_hi, Wqkf_lo);

  // Encoder: 128 steps, ONE persistent cooperative launch
  {
    void* ea[] = {
      (void*)&hfA_hi, (void*)&hfA_lo, (void*)&hfB_hi, (void*)&hfB_lo,
      (void*)&Wdhf_hi, (void*)&Wdhf_lo, (void*)&Wxf_hi, (void*)&Wxf_lo,
      (void*)&xsf_hi, (void*)&xsf_lo, (void*)&enc_b, (void*)&c, (void*)&buf,
      (void*)&bar
    };
    hipLaunchCooperativeKernel((void*)enc_all, dim3(ENCB), dim3(512), ea, 0,
                               stream);
  }
  // t=127 (odd) wrote hfA -> final h there

  dec_prep<<<NB, 256, 0, stream>>>(hfA_hi, hfA_lo, c, qA_hi, qA_lo);
  gemm_kp<<<dim3(302, 4), 256, 0, stream>>>(buf, Wqkf_hi, Wqkf_lo, kp);
  zero_dbar<<<1, 128, 0, stream>>>(dbar);

  // decoder weight transforms (overwrite encoder overlays)
  frag_w4<<<4096, 256, 0, stream>>>(dec_Wih, 2048, 6, Wdxf_hi, Wdxf_lo, 1048576);
  frag_w4<<<2048, 256, 0, stream>>>(dec_Whh, 1024, 5, Wdhf_hi, Wdhf_lo, 524288);

  // Decoder: 24 steps, ONE persistent cooperative launch (256 blocks)
  {
    void* da[] = {
      (void*)&Xf_hi, (void*)&Xf_lo, (void*)&qA_hi, (void*)&qA_lo,
      (void*)&qB_hi, (void*)&qB_lo, (void*)&Wqkf_hi, (void*)&Wqkf_lo,
      (void*)&Wdxf_hi, (void*)&Wdxf_lo, (void*)&Wdhf_hi, (void*)&Wdhf_lo,
      (void*)&dec_b, (void*)&c, (void*)&buf, (void*)&kp, (void*)&qkout,
      (void*)&attn_Wv, (void*)&out_w, (void*)&out_b, (void*)&out,
      (void*)&dbar
    };
    hipLaunchCooperativeKernel((void*)dec_all, dim3(DECB), dim3(512), da, 0,
                               stream);
  }
}